// Round 11
// baseline (188.315 us; speedup 1.0000x reference)
//
#include <hip/hip_runtime.h>
#include <stdint.h>

#define IN_F   4096
#define OUT_F  4096
#define BATCH  128
#define NNZ    1600000
#define BK     64

typedef __bf16 bf16x8 __attribute__((ext_vector_type(8)));
typedef float  floatx4 __attribute__((ext_vector_type(4)));

// ---------- helpers ----------
__device__ __forceinline__ unsigned f2bf(float f) {  // fp32 -> bf16 bits (RNE)
  unsigned u = __float_as_uint(f);
  return (u + 0x7fffu + ((u >> 16) & 1u)) >> 16;
}

// ---------- K0: zero dense W (bf16, as 2.1M uint4) ----------
__global__ __launch_bounds__(256) void k_zeroW(uint4* __restrict__ W4) {
  const int i = blockIdx.x * 1024 + threadIdx.x;     // 2048 blocks
  const uint4 z = make_uint4(0u, 0u, 0u, 0u);
  W4[i] = z; W4[i + 256] = z; W4[i + 512] = z; W4[i + 768] = z;
}

// ---------- K1: inp fp32 [128][4096] -> bf16 A [128][4096] (row-major, no transpose) --
__global__ __launch_bounds__(256) void k_prep2(const float* __restrict__ inp,
                                               uint2* __restrict__ A2) {
  const int i = blockIdx.x * 256 + threadIdx.x;      // 512 blocks; i over float4s
  const float4 x = ((const float4*)inp)[i];
  A2[i] = make_uint2(f2bf(x.x) | (f2bf(x.y) << 16), f2bf(x.z) | (f2bf(x.w) << 16));
}

// ---------- K2: scatter nnz into dense bf16 W with CAS add (duplicates sum) ----------
__device__ __forceinline__ void bf16_cas_add(unsigned* __restrict__ W, int r, int c,
                                             float v) {
  const unsigned idx = ((unsigned)r << 12) | (unsigned)c;
  unsigned* p = W + (idx >> 1);
  const bool hi = idx & 1u;
  unsigned old = *p;
  while (true) {
    const unsigned assumed = old;
    const unsigned half = hi ? (assumed >> 16) : (assumed & 0xffffu);
    const float f = __uint_as_float(half << 16) + v;
    const unsigned nb = f2bf(f) & 0xffffu;
    const unsigned neww = hi ? ((assumed & 0x0000ffffu) | (nb << 16))
                             : ((assumed & 0xffff0000u) | nb);
    old = atomicCAS(p, assumed, neww);
    if (old == assumed) break;
  }
}

__global__ __launch_bounds__(256) void k_scat(const float* __restrict__ vals,
                                              const int* __restrict__ rows,
                                              const int* __restrict__ cols,
                                              unsigned* __restrict__ W) {
  const int i = (blockIdx.x * 256 + threadIdx.x) * 4;
  if (i >= NNZ) return;                              // NNZ % 4 == 0
  const float4 v = *(const float4*)(vals + i);
  const int4   r = *(const int4*)(rows + i);
  const int4   c = *(const int4*)(cols + i);
  bf16_cas_add(W, r.x, c.x, v.x);
  bf16_cas_add(W, r.y, c.y, v.y);
  bf16_cas_add(W, r.z, c.z, v.z);
  bf16_cas_add(W, r.w, c.w, v.w);
}

// ---------- K3: dense GEMM  out[m][n] = bias[n] + sum_k A[m][k]*W[n][k] ----------
// 512 blocks: m-tile = bx&3 (32 rows of batch), n-tile = bx>>2 (32 rows of W).
// 256 threads = 4 waves; wave owns a 16x16 C-tile via mfma_f32_16x16x32_bf16.
// Verified layouts (m89/m97): A-frag A[m=lane&15][k=quad*8+j]; B^T loaded same way;
// C/D: col(n)=lane&15, row(m)=quad*4+reg.
__global__ __launch_bounds__(256) void k_gemm(const unsigned short* __restrict__ A,
                                              const unsigned short* __restrict__ W,
                                              const float* __restrict__ bias,
                                              float* __restrict__ out) {
  __shared__ unsigned short Al[32][72];   // +8 pad: conflict-light, keeps 16B align
  __shared__ unsigned short Wl[32][72];
  const int t    = threadIdx.x;
  const int lane = t & 63;
  const int wid  = t >> 6;
  const int m0 = (blockIdx.x & 3) * 32;
  const int n0 = (blockIdx.x >> 2) * 32;
  const int wm = (wid & 1) * 16;
  const int wn = (wid >> 1) * 16;
  const int fr = lane & 15;
  const int qd = lane >> 4;

  const int arow = t >> 3;               // 0..31
  const int achk = (t & 7) * 8;          // 0..56

  floatx4 acc = {0.f, 0.f, 0.f, 0.f};

  const unsigned short* __restrict__ Ab = A + (size_t)(m0 + arow) * IN_F + achk;
  const unsigned short* __restrict__ Wb = W + (size_t)(n0 + arow) * IN_F + achk;

  for (int k0 = 0; k0 < IN_F; k0 += BK) {
    __syncthreads();
    *(uint4*)&Al[arow][achk] = *(const uint4*)(Ab + k0);
    *(uint4*)&Wl[arow][achk] = *(const uint4*)(Wb + k0);
    __syncthreads();
    #pragma unroll
    for (int ks = 0; ks < 2; ++ks) {
      const bf16x8 af = *(const bf16x8*)&Al[wm + fr][ks * 32 + qd * 8];
      const bf16x8 wf = *(const bf16x8*)&Wl[wn + fr][ks * 32 + qd * 8];
      acc = __builtin_amdgcn_mfma_f32_16x16x32_bf16(af, wf, acc, 0, 0, 0);
    }
  }

  const int gn = n0 + wn + fr;
  const float bs = bias[gn];
  #pragma unroll
  for (int reg = 0; reg < 4; ++reg) {
    const int gm = m0 + wm + qd * 4 + reg;
    out[(size_t)gm * OUT_F + gn] = acc[reg] + bs;
  }
}

// ---------- fallback (tiny workspace): correct but slow ----------
__global__ __launch_bounds__(256) void k_init_out(const float* __restrict__ bias,
                                                  float* __restrict__ out) {
  const int i = blockIdx.x * 256 + threadIdx.x;
  out[i] = bias[i & (OUT_F - 1)];
}
__global__ __launch_bounds__(256) void k_atomic(const float* __restrict__ vals,
                                                const int* __restrict__ rows,
                                                const int* __restrict__ cols,
                                                const float* __restrict__ inp,
                                                float* __restrict__ out) {
  const int i = blockIdx.x * 256 + threadIdx.x;
  if (i >= NNZ) return;
  const float v = vals[i];
  const int   r = rows[i];
  const int   c = cols[i];
  for (int b = 0; b < BATCH; ++b)
    atomicAdd(&out[(size_t)b * OUT_F + r], v * inp[(size_t)b * IN_F + c]);
}

extern "C" void kernel_launch(void* const* d_in, const int* in_sizes, int n_in,
                              void* d_out, int out_size, void* d_ws, size_t ws_size,
                              hipStream_t stream) {
  const float* inp      = (const float*)d_in[0];
  const float* w_values = (const float*)d_in[1];
  const int*   w_rows   = (const int*)d_in[2];
  const int*   w_cols   = (const int*)d_in[3];
  const float* bias     = (const float*)d_in[4];
  float*       out      = (float*)d_out;

  const size_t A_bytes = (size_t)BATCH * IN_F * 2;        // 1 MB bf16
  const size_t W_bytes = (size_t)OUT_F * IN_F * 2;        // 33.5 MB bf16
  const size_t need = A_bytes + W_bytes;

  if (ws_size >= need) {
    char* ws = (char*)d_ws;
    unsigned short* A = (unsigned short*)ws;   ws += A_bytes;
    unsigned short* W = (unsigned short*)ws;

    k_zeroW<<<2048, 256, 0, stream>>>((uint4*)W);
    k_prep2<<<(BATCH * IN_F / 4) / 256, 256, 0, stream>>>(inp, (uint2*)A);
    k_scat<<<(NNZ / 4 + 255) / 256, 256, 0, stream>>>(w_values, w_rows, w_cols,
                                                      (unsigned*)W);
    k_gemm<<<4 * (OUT_F / 32), 256, 0, stream>>>(A, W, bias, out);
  } else {
    k_init_out<<<(BATCH * OUT_F) / 256, 256, 0, stream>>>(bias, out);
    k_atomic<<<(NNZ + 255) / 256, 256, 0, stream>>>(w_values, w_rows, w_cols, inp, out);
  }
}

// Round 12
// 127.120 us; speedup vs baseline: 1.4814x; 1.4814x over previous
//
#include <hip/hip_runtime.h>
#include <stdint.h>

#define IN_F     4096
#define OUT_F    4096
#define BATCH    128
#define NNZ      1600000
#define NSEG     250       // segments; block s of segscat owns entries [s*6400, +6400)
#define CHUNKSEG 6400      // NNZ / NSEG exactly
#define CNTR     4096      // cntoff stride per segment (= OUT_F)

typedef __bf16 bf16x8 __attribute__((ext_vector_type(8)));
typedef float  floatx4 __attribute__((ext_vector_type(4)));

// ---------- helpers ----------
__device__ __forceinline__ unsigned f2bf(float f) {  // fp32 -> bf16 bits (RNE)
  unsigned u = __float_as_uint(f);
  return (u + 0x7fffu + ((u >> 16) & 1u)) >> 16;
}

// ---------- K1: inp fp32 [128][4096] -> bf16 A [128][4096] row-major ----------
__global__ __launch_bounds__(256) void k_prep2(const float* __restrict__ inp,
                                               uint2* __restrict__ A2) {
  const int i = blockIdx.x * 256 + threadIdx.x;      // 512 blocks; i over float4s
  const float4 x = ((const float4*)inp)[i];
  A2[i] = make_uint2(f2bf(x.x) | (f2bf(x.y) << 16), f2bf(x.z) | (f2bf(x.w) << 16));
}

// ---------- K2: per-block LDS counting sort -> compact entry stream + (off|cnt) ------
// (verified round 10, unchanged)
__global__ __launch_bounds__(1024) void k_segscat2(const float* __restrict__ vals,
                                                   const int* __restrict__ rows,
                                                   const int* __restrict__ cols,
                                                   unsigned* __restrict__ cntoff,
                                                   unsigned* __restrict__ gentries) {
  __shared__ unsigned pos[OUT_F];
  __shared__ unsigned sebuf[CHUNKSEG];
  __shared__ unsigned wsum[16];
  const int t = threadIdx.x;
  const int s = blockIdx.x;
  const int lane = t & 63;
  const int wid  = t >> 6;

  for (int i = t; i < OUT_F; i += 1024) pos[i] = 0u;
  __syncthreads();

  const size_t vbase = (size_t)s * (CHUNKSEG / 4);
  const size_t ja = vbase + t;
  const int4   ra = ((const int4*)rows)[ja];
  const int4   ca = ((const int4*)cols)[ja];
  const float4 va = ((const float4*)vals)[ja];
  const bool hasB = (t + 1024) < (CHUNKSEG / 4);
  int4 rb = make_int4(0, 0, 0, 0), cb = rb;
  float4 vb = make_float4(0.f, 0.f, 0.f, 0.f);
  if (hasB) {
    const size_t jb = ja + 1024;
    rb = ((const int4*)rows)[jb];
    cb = ((const int4*)cols)[jb];
    vb = ((const float4*)vals)[jb];
  }

  atomicAdd(&pos[ra.x], 1u); atomicAdd(&pos[ra.y], 1u);
  atomicAdd(&pos[ra.z], 1u); atomicAdd(&pos[ra.w], 1u);
  if (hasB) {
    atomicAdd(&pos[rb.x], 1u); atomicAdd(&pos[rb.y], 1u);
    atomicAdd(&pos[rb.z], 1u); atomicAdd(&pos[rb.w], 1u);
  }
  __syncthreads();

  const unsigned c0 = pos[4 * t], c1 = pos[4 * t + 1];
  const unsigned c2 = pos[4 * t + 2], c3 = pos[4 * t + 3];
  const unsigned tsum = c0 + c1 + c2 + c3;
  unsigned incl = tsum;
  #pragma unroll
  for (int d = 1; d < 64; d <<= 1) {
    const unsigned u = __shfl_up(incl, d, 64);
    if (lane >= d) incl += u;
  }
  if (lane == 63) wsum[wid] = incl;
  __syncthreads();
  if (wid == 0) {
    const unsigned v = (lane < 16) ? wsum[lane] : 0u;
    unsigned inc2 = v;
    #pragma unroll
    for (int d = 1; d < 16; d <<= 1) {
      const unsigned u = __shfl_up(inc2, d, 64);
      if (lane >= d) inc2 += u;
    }
    if (lane < 16) wsum[lane] = inc2 - v;
  }
  __syncthreads();
  const unsigned base = wsum[wid] + (incl - tsum);
  const unsigned o0 = base, o1 = o0 + c0, o2 = o1 + c1, o3 = o2 + c2;
  ((uint4*)(cntoff + (size_t)s * CNTR))[t] =
      make_uint4((o0 << 16) | c0, (o1 << 16) | c1, (o2 << 16) | c2, (o3 << 16) | c3);
  __syncthreads();
  pos[4 * t] = o0; pos[4 * t + 1] = o1; pos[4 * t + 2] = o2; pos[4 * t + 3] = o3;
  __syncthreads();

  unsigned p;
  p = atomicAdd(&pos[ra.x], 1u); sebuf[p] = (f2bf(va.x) << 16) | (unsigned)ca.x;
  p = atomicAdd(&pos[ra.y], 1u); sebuf[p] = (f2bf(va.y) << 16) | (unsigned)ca.y;
  p = atomicAdd(&pos[ra.z], 1u); sebuf[p] = (f2bf(va.z) << 16) | (unsigned)ca.z;
  p = atomicAdd(&pos[ra.w], 1u); sebuf[p] = (f2bf(va.w) << 16) | (unsigned)ca.w;
  if (hasB) {
    p = atomicAdd(&pos[rb.x], 1u); sebuf[p] = (f2bf(vb.x) << 16) | (unsigned)cb.x;
    p = atomicAdd(&pos[rb.y], 1u); sebuf[p] = (f2bf(vb.y) << 16) | (unsigned)cb.y;
    p = atomicAdd(&pos[rb.z], 1u); sebuf[p] = (f2bf(vb.z) << 16) | (unsigned)cb.z;
    p = atomicAdd(&pos[rb.w], 1u); sebuf[p] = (f2bf(vb.w) << 16) | (unsigned)cb.w;
  }
  __syncthreads();

  uint4* __restrict__ dst = (uint4*)(gentries + (size_t)s * CHUNKSEG);
  const uint4* __restrict__ srcv = (const uint4*)sebuf;
  dst[t] = srcv[t];
  if (hasB) dst[t + 1024] = srcv[t + 1024];
}

// ---------- K3: densify — one block per W row; fp32 LDS accumulate, coalesced store --
__global__ __launch_bounds__(256) void k_dens(const unsigned* __restrict__ cntoff,
                                              const unsigned* __restrict__ gentries,
                                              unsigned* __restrict__ W) {
  __shared__ float facc[IN_F];
  const int t = threadIdx.x;
  const int r = blockIdx.x;
  #pragma unroll
  for (int k = 0; k < 16; ++k) facc[t + 256 * k] = 0.f;
  __syncthreads();

  if (t < NSEG) {
    const unsigned co  = cntoff[(size_t)t * CNTR + r];
    const unsigned c   = co & 0xffffu;
    const unsigned off = co >> 16;
    const unsigned* __restrict__ src = gentries + (size_t)t * CHUNKSEG + off;
    for (unsigned j = 0; j < c; ++j) {
      const unsigned e = src[j];
      atomicAdd(&facc[e & 0xffffu], __uint_as_float(e & 0xffff0000u));
    }
  }
  __syncthreads();

  uint4* __restrict__ dst = (uint4*)(W + (size_t)r * (IN_F / 2));
  const int base = t * 16;
  unsigned u[8];
  #pragma unroll
  for (int k = 0; k < 8; ++k)
    u[k] = f2bf(facc[base + 2 * k]) | (f2bf(facc[base + 2 * k + 1]) << 16);
  dst[2 * t]     = make_uint4(u[0], u[1], u[2], u[3]);
  dst[2 * t + 1] = make_uint4(u[4], u[5], u[6], u[7]);
}

// ---------- K4: GEMM — m=128 (all batch), n-tile 64, K-split 8; W read once ----------
// Fragment mapping copied from round-11 verified kernel.
__global__ __launch_bounds__(256) void k_gemm(const unsigned short* __restrict__ A,
                                              const unsigned short* __restrict__ W,
                                              float* __restrict__ part) {
  __shared__ unsigned short Al[128][72];   // +8 pad
  __shared__ unsigned short Wl[64][72];
  const int t    = threadIdx.x;
  const int lane = t & 63;
  const int wid  = t >> 6;
  const int n0 = (blockIdx.x >> 3) * 64;
  const int kb = (blockIdx.x & 7) * 512;
  const int fr = lane & 15;
  const int qd = lane >> 4;
  const int wn = wid * 16;

  const int arow = t >> 1;           // 0..127
  const int aseg = (t & 1) * 32;     // 0 / 32
  const int wrow = t >> 2;           // 0..63
  const int wseg = (t & 3) * 16;

  floatx4 acc[8];
  #pragma unroll
  for (int i = 0; i < 8; ++i) acc[i] = (floatx4){0.f, 0.f, 0.f, 0.f};

  for (int cc = 0; cc < 8; ++cc) {
    const int k0 = kb + cc * 64;
    __syncthreads();
    {
      const uint4* sa = (const uint4*)(A + (size_t)arow * IN_F + k0 + aseg);
      uint4* da = (uint4*)&Al[arow][aseg];
      da[0] = sa[0]; da[1] = sa[1]; da[2] = sa[2]; da[3] = sa[3];
      const uint4* sw = (const uint4*)(W + (size_t)(n0 + wrow) * IN_F + k0 + wseg);
      uint4* dw = (uint4*)&Wl[wrow][wseg];
      dw[0] = sw[0]; dw[1] = sw[1];
    }
    __syncthreads();
    #pragma unroll
    for (int ks = 0; ks < 2; ++ks) {
      const bf16x8 wf = *(const bf16x8*)&Wl[wn + fr][ks * 32 + qd * 8];
      #pragma unroll
      for (int mt = 0; mt < 8; ++mt) {
        const bf16x8 af = *(const bf16x8*)&Al[mt * 16 + fr][ks * 32 + qd * 8];
        acc[mt] = __builtin_amdgcn_mfma_f32_16x16x32_bf16(af, wf, acc[mt], 0, 0, 0);
      }
    }
  }

  float* __restrict__ p = part + (size_t)(blockIdx.x & 7) * BATCH * OUT_F;
  const int gn = n0 + wn + fr;
  #pragma unroll
  for (int mt = 0; mt < 8; ++mt) {
    #pragma unroll
    for (int reg = 0; reg < 4; ++reg) {
      const int gm = mt * 16 + qd * 4 + reg;
      p[(size_t)gm * OUT_F + gn] = acc[mt][reg];
    }
  }
}

// ---------- K5: reduce 8 partial planes + bias -> out ----------
__global__ __launch_bounds__(256) void k_red(const float4* __restrict__ part,
                                             const float* __restrict__ bias,
                                             float4* __restrict__ out4) {
  const int i = blockIdx.x * 256 + threadIdx.x;   // 131072 float4s
  float4 s = ((const float4*)bias)[i & 1023];
  #pragma unroll
  for (int p = 0; p < 8; ++p) {
    const float4 v = part[(size_t)p * (BATCH * OUT_F / 4) + i];
    s.x += v.x; s.y += v.y; s.z += v.z; s.w += v.w;
  }
  out4[i] = s;
}

// ---------- fallback (tiny workspace): correct but slow ----------
__global__ __launch_bounds__(256) void k_init_out(const float* __restrict__ bias,
                                                  float* __restrict__ out) {
  const int i = blockIdx.x * 256 + threadIdx.x;
  out[i] = bias[i & (OUT_F - 1)];
}
__global__ __launch_bounds__(256) void k_atomic(const float* __restrict__ vals,
                                                const int* __restrict__ rows,
                                                const int* __restrict__ cols,
                                                const float* __restrict__ inp,
                                                float* __restrict__ out) {
  const int i = blockIdx.x * 256 + threadIdx.x;
  if (i >= NNZ) return;
  const float v = vals[i];
  const int   r = rows[i];
  const int   c = cols[i];
  for (int b = 0; b < BATCH; ++b)
    atomicAdd(&out[(size_t)b * OUT_F + r], v * inp[(size_t)b * IN_F + c]);
}

extern "C" void kernel_launch(void* const* d_in, const int* in_sizes, int n_in,
                              void* d_out, int out_size, void* d_ws, size_t ws_size,
                              hipStream_t stream) {
  const float* inp      = (const float*)d_in[0];
  const float* w_values = (const float*)d_in[1];
  const int*   w_rows   = (const int*)d_in[2];
  const int*   w_cols   = (const int*)d_in[3];
  const float* bias     = (const float*)d_in[4];
  float*       out      = (float*)d_out;

  const size_t A_bytes    = (size_t)BATCH * IN_F * 2;        // 1 MB
  const size_t co_bytes   = (size_t)NSEG * CNTR * 4;         // 4.1 MB
  const size_t ent_bytes  = (size_t)NSEG * CHUNKSEG * 4;     // 6.4 MB
  const size_t W_bytes    = (size_t)OUT_F * IN_F * 2;        // 33.5 MB
  const size_t part_bytes = (size_t)8 * BATCH * OUT_F * 4;   // 16.8 MB
  const size_t need = A_bytes + co_bytes + ent_bytes + W_bytes + part_bytes;

  if (ws_size >= need) {
    char* ws = (char*)d_ws;
    unsigned short* A        = (unsigned short*)ws;  ws += A_bytes;
    unsigned*       cntoff   = (unsigned*)ws;        ws += co_bytes;
    unsigned*       gentries = (unsigned*)ws;        ws += ent_bytes;
    unsigned short* W        = (unsigned short*)ws;  ws += W_bytes;
    float*          part     = (float*)ws;

    k_prep2<<<(BATCH * IN_F / 4) / 256, 256, 0, stream>>>(inp, (uint2*)A);
    k_segscat2<<<NSEG, 1024, 0, stream>>>(w_values, w_rows, w_cols, cntoff, gentries);
    k_dens<<<OUT_F, 256, 0, stream>>>(cntoff, gentries, (unsigned*)W);
    k_gemm<<<(OUT_F / 64) * 8, 256, 0, stream>>>(A, W, part);
    k_red<<<(BATCH * OUT_F / 4) / 256, 256, 0, stream>>>((const float4*)part, bias,
                                                         (float4*)out);
  } else {
    k_init_out<<<(BATCH * OUT_F) / 256, 256, 0, stream>>>(bias, out);
    k_atomic<<<(NNZ + 255) / 256, 256, 0, stream>>>(w_values, w_rows, w_cols, inp, out);
  }
}